// Round 9
// baseline (183.754 us; speedup 1.0000x reference)
//
#include <hip/hip_runtime.h>

// Problem constants (from reference setup_inputs)
constexpr int K    = 64;
constexpr int N    = 1024;
constexpr int DIN  = 16;
constexpr int H1   = 4;
constexpr int DOUT = 8;
constexpr int FC1  = 54;

#define ALPHA_F   (0.01f)
#define LOG2E_F   (1.4426950408889634f)

__device__ inline float fast_exp2(float x) {
#if __has_builtin(__builtin_amdgcn_exp2f)
    return __builtin_amdgcn_exp2f(x);      // raw v_exp_f32
#else
    return __expf(x * 0.6931471805599453f);
#endif
}

// ---------------------------------------------------------------------------
// prep kernel: three independent jobs split by blockIdx range.
//  A) blocks [0,2048):    maskT[jw*N+i] = ballot bits of adj[i][jw*64+lane]
//  B) blocks [2048,2112): LDS-tile transpose fc1_w [8192,54] -> wt [54,8192]
//  C) blocks [2112,2240): gat1 projection: h1 = X@W1; f11/f21 logits *log2e
// ---------------------------------------------------------------------------
__global__ __launch_bounds__(512) void prep_kernel(
        const int* __restrict__ adj, unsigned long long* __restrict__ maskT,
        const float* __restrict__ fc1w, float* __restrict__ wt,
        const float* __restrict__ X, const float* __restrict__ W1,
        const float* __restrict__ a1,
        float* __restrict__ h1, float* __restrict__ f11, float* __restrict__ f21) {
    int b = blockIdx.x;
    if (b < 2048) {
        int wave = threadIdx.x >> 6, lane = threadIdx.x & 63;
        int wid = b * 8 + wave;            // 0..16383
        int jw  = wid >> 10;               // 0..15
        int i   = wid & 1023;
        int v = adj[i * N + (jw << 6) + lane];        // coalesced 256B/wave
        unsigned long long m = __ballot(v > 0);       // bit lane = adj>0
        if (lane == 0) maskT[jw * N + i] = m;
    } else if (b < 2112) {
        // transpose 128-row tile: coalesced read + coalesced write via LDS
        __shared__ float tile[128 * FC1];
        const int m0 = (b - 2048) * 128;
        const float* src = fc1w + (size_t)m0 * FC1;
        for (int idx = threadIdx.x; idx < 128 * FC1; idx += 512)
            tile[idx] = src[idx];                     // consecutive
        __syncthreads();
        for (int idx = threadIdx.x; idx < 128 * FC1; idx += 512) {
            int c = idx >> 7, mm = idx & 127;
            wt[(size_t)c * (N * DOUT) + m0 + mm] = tile[mm * FC1 + c];
        }
    } else {
        int idx = (b - 2112) * 512 + threadIdx.x;     // < 65536 : k*N+n
        const float4* x4 = (const float4*)(X + (size_t)idx * DIN);
        float h[H1] = {0.f, 0.f, 0.f, 0.f};
        #pragma unroll
        for (int q = 0; q < 4; q++) {
            float4 xv = x4[q];
            #pragma unroll
            for (int f = 0; f < H1; f++) {
                h[f] += xv.x * W1[(q * 4 + 0) * H1 + f] + xv.y * W1[(q * 4 + 1) * H1 + f]
                      + xv.z * W1[(q * 4 + 2) * H1 + f] + xv.w * W1[(q * 4 + 3) * H1 + f];
            }
        }
        float s1 = 0.f, s2 = 0.f;
        #pragma unroll
        for (int f = 0; f < H1; f++) { s1 += h[f] * a1[f]; s2 += h[f] * a1[H1 + f]; }
        *(float4*)(h1 + (size_t)idx * H1) = make_float4(h[0], h[1], h[2], h[3]);
        f11[idx] = s1 * LOG2E_F;           // pre-scaled for exp2
        f21[idx] = s2 * LOG2E_F;
    }
}

// ---------------------------------------------------------------------------
// Attention v9: v8's SMEM-broadcast structure at DOUBLE the occupancy.
// Block = 512 thr (8 waves), 64 rows (1 row per lane); waves split j 8 x 128
// (exactly 2 mask words each).  wv via readfirstlane keeps the j-chunk base
// SGPR-resident -> f2[j]/h[j][:] addresses provably wave-uniform -> s_load
// batches on the lgkmcnt path; VMEM carries only the 2 per-lane mask words
// per row.  Grid K*16 = 1024 blocks -> 4 blocks/CU -> 32 waves/CU
// (8 waves/SIMD) for latency hiding; VGPR(36) fits __launch_bounds__(512,8).
// Softmax without max-subtract (logits pre-scaled by log2e -> raw exp2;
// mask zeroes p after exp -> exact).  FUSE: layer-2 projection in epilogue.
// ---------------------------------------------------------------------------
template <int F, bool FUSE>
__global__ __launch_bounds__(512, 8) void gat_attn9(
        const unsigned long long* __restrict__ maskT,  // [16][N]
        const float* __restrict__ h,    // [K,N,F]
        const float* __restrict__ f1,   // [K,N]  (x log2e)
        const float* __restrict__ f2,   // [K,N]  (x log2e)
        const float* __restrict__ W2,   // [4,8]  (FUSE only)
        const float* __restrict__ a2,   // [16]   (FUSE only)
        float* __restrict__ o_x,        // FUSE: h2 [K,N,8]; else out [K,N,F]
        float* __restrict__ o_f1,       // FUSE: f12 (x log2e)
        float* __restrict__ o_f2) {     // FUSE: f22 (x log2e)
    __shared__ float part[8 * 64 * (F + 1)];     // [wave][row][F+1]

    const int tid  = threadIdx.x;
    const int lane = tid & 63;
    const int wv   = __builtin_amdgcn_readfirstlane(tid >> 6);  // SGPR wave id
    const int k    = blockIdx.x >> 4;            // 16 blocks per k
    const int iset = blockIdx.x & 15;
    const int i    = iset * 64 + lane;

    const float  f1i = f1[k * N + i];
    const float* f2k = f2 + k * N;               // uniform base
    const float* hk  = h + (size_t)k * N * F;    // uniform base

    float s = 0.f;
    float acc[F];
    #pragma unroll
    for (int f = 0; f < F; f++) acc[f] = 0.f;

    const int j0 = wv * 128;                     // SGPR chunk base
    #pragma unroll
    for (int w = 0; w < 2; w++) {                // 2 mask words of 64 j
        const int jb = j0 + w * 64;
        const unsigned long long mw = maskT[(jb >> 6) * N + i];  // per-lane VMEM
        #pragma unroll
        for (int half = 0; half < 2; half++) {
            const unsigned wb = half ? (unsigned)(mw >> 32) : (unsigned)mw;
            const int jh = jb + half * 32;
            #pragma unroll 8
            for (int t = 0; t < 32; t++) {
                const int j = jh + t;            // uniform
                const float f2j = f2k[j];        // s_load
                const float* hj = hk + (size_t)j * F;   // uniform
                float y = f1i + f2j;
                float e = fmaxf(y, ALPHA_F * y); // leaky (pre-scaled by log2e)
                float p = fast_exp2(e);
                p = (wb & (1u << t)) ? p : 0.f;  // mask -> exact 0
                s += p;
                #pragma unroll
                for (int f = 0; f < F; f++) acc[f] += p * hj[f];  // sgpr operand
            }
        }
    }

    // per-wave partials (stride F+1 odd -> conflict-free)
    {
        float* pp = part + (wv * 64 + lane) * (F + 1);
        pp[0] = s;
        #pragma unroll
        for (int f = 0; f < F; f++) pp[1 + f] = acc[f];
    }
    __syncthreads();

    if (tid < 64) {
        const int r = tid;
        float st = 0.f;
        float at[F];
        #pragma unroll
        for (int f = 0; f < F; f++) at[f] = 0.f;
        #pragma unroll
        for (int w = 0; w < 8; w++) {
            const float* pp = part + (w * 64 + r) * (F + 1);
            st += pp[0];
            #pragma unroll
            for (int f = 0; f < F; f++) at[f] += pp[1 + f];
        }
        const float inv = (st > 0.f) ? 1.f / st : 0.f;
        const int orow = k * N + iset * 64 + r;
        float xo[F];
        #pragma unroll
        for (int f = 0; f < F; f++) xo[f] = fmaxf(at[f] * inv, 0.f);  // relu

        if constexpr (FUSE) {
            // layer-2 projection: h2 = xo(4) @ W2(4x8); logits vs a2 (x log2e)
            float hv[DOUT];
            #pragma unroll
            for (int f = 0; f < DOUT; f++) {
                hv[f] = xo[0] * W2[f]      + xo[1] * W2[8 + f]
                      + xo[2] * W2[16 + f] + xo[3] * W2[24 + f];
            }
            float t1 = 0.f, t2 = 0.f;
            #pragma unroll
            for (int f = 0; f < DOUT; f++) { t1 += hv[f] * a2[f]; t2 += hv[f] * a2[DOUT + f]; }
            float* op = o_x + (size_t)orow * DOUT;
            *(float4*)op       = make_float4(hv[0], hv[1], hv[2], hv[3]);
            *(float4*)(op + 4) = make_float4(hv[4], hv[5], hv[6], hv[7]);
            o_f1[orow] = t1 * LOG2E_F;
            o_f2[orow] = t2 * LOG2E_F;
        } else {
            float* op = o_x + (size_t)orow * F;
            *(float4*)op = make_float4(xo[0], xo[1], xo[2], xo[3]);
            if (F == 8)
                *(float4*)(op + 4) = make_float4(xo[4], xo[5], xo[6], xo[7]);
        }
    }
}

// ---------------------------------------------------------------------------
// FC head, fully fused: one 1024-thread block per k.
// Phase 1: 16 waves compute y[c] = relu(x2[k,:].wt[c,:] + b[c]) into LDS
//          (x2[k] is 32 KB -> L1-resident across the 54 c-dots; wt L2-hot).
// Phase 2: thread n computes out[k,n] = y . out_w[:,n] + out_b[n].
// ---------------------------------------------------------------------------
__global__ __launch_bounds__(1024) void fchead_kernel(
        const float* __restrict__ x2, const float* __restrict__ wt,
        const float* __restrict__ fc1b,
        const float* __restrict__ outw, const float* __restrict__ outb,
        float* __restrict__ out) {
    __shared__ float y_lds[FC1];
    const int k    = blockIdx.x;
    const int wave = threadIdx.x >> 6;
    const int lane = threadIdx.x & 63;

    const float4* x4 = (const float4*)(x2 + (size_t)k * N * DOUT);
    for (int c = wave; c < FC1; c += 16) {
        const float4* w4 = (const float4*)(wt + (size_t)c * N * DOUT);
        float s0 = 0.f, s1 = 0.f;
        #pragma unroll
        for (int q = 0; q < 32; q += 2) {
            float4 a0 = x4[q * 64 + lane],        w0 = w4[q * 64 + lane];
            float4 a1 = x4[(q + 1) * 64 + lane],  w1 = w4[(q + 1) * 64 + lane];
            s0 += a0.x * w0.x + a0.y * w0.y + a0.z * w0.z + a0.w * w0.w;
            s1 += a1.x * w1.x + a1.y * w1.y + a1.z * w1.z + a1.w * w1.w;
        }
        float s = s0 + s1;
        #pragma unroll
        for (int off = 32; off > 0; off >>= 1) s += __shfl_xor(s, off);
        if (lane == 0) y_lds[c] = fmaxf(s + fc1b[c], 0.f);
    }
    __syncthreads();

    const int n = threadIdx.x;                   // 0..1023
    float s = outb[n];
    #pragma unroll 6
    for (int c = 0; c < FC1; c++) s += y_lds[c] * outw[(size_t)c * N + n];
    out[(size_t)k * N + n] = s;
}

// ---------------------------------------------------------------------------
extern "C" void kernel_launch(void* const* d_in, const int* in_sizes, int n_in,
                              void* d_out, int out_size, void* d_ws, size_t ws_size,
                              hipStream_t stream) {
    const float* X     = (const float*)d_in[0];
    const int*   adj   = (const int*)  d_in[1];
    const float* W1    = (const float*)d_in[2];
    const float* a1    = (const float*)d_in[3];
    const float* W2    = (const float*)d_in[4];
    const float* a2    = (const float*)d_in[5];
    const float* fc1w  = (const float*)d_in[6];
    const float* fc1b  = (const float*)d_in[7];
    const float* outw  = (const float*)d_in[8];
    const float* outb  = (const float*)d_in[9];
    float* out = (float*)d_out;

    // Workspace layout (floats); ~8 MB total
    float* ws  = (float*)d_ws;
    float* h1  = ws;                       // 262144
    float* f11 = h1  + 262144;             // 65536
    float* f21 = f11 + 65536;              // 65536
    float* h2  = f21 + 65536;              // 524288
    float* f12 = h2  + 524288;             // 65536
    float* f22 = f12 + 65536;              // 65536
    float* x2  = f22 + 65536;              // 524288
    float* wt  = x2  + 524288;             // 442368
    unsigned long long* mT = (unsigned long long*)(wt + 442368);  // 16384 u64

    // 1) fused prep: mask pack (transposed) + fc1_w transpose + gat1 proj
    prep_kernel<<<dim3(2240), dim3(512), 0, stream>>>(
        adj, mT, fc1w, wt, X, W1, a1, h1, f11, f21);

    // 2) layer-1 attention (SMEM-broadcast, 8 waves/SIMD), + layer-2 proj
    gat_attn9<4, true><<<dim3(K * 16), dim3(512), 0, stream>>>(
        mT, h1, f11, f21, W2, a2, h2, f12, f22);

    // 3) layer-2 attention
    gat_attn9<8, false><<<dim3(K * 16), dim3(512), 0, stream>>>(
        mT, h2, f12, f22, nullptr, nullptr, x2, nullptr, nullptr);

    // 4) fused FC head (fc1 + fc2)
    fchead_kernel<<<dim3(K), dim3(1024), 0, stream>>>(
        x2, wt, fc1b, outw, outb, out);
}

// Round 10
// 146.066 us; speedup vs baseline: 1.2580x; 1.2580x over previous
//
#include <hip/hip_runtime.h>

// Problem constants (from reference setup_inputs)
constexpr int K    = 64;
constexpr int N    = 1024;
constexpr int DIN  = 16;
constexpr int H1   = 4;
constexpr int DOUT = 8;
constexpr int FC1  = 54;

#define ALPHA_F   (0.01f)
#define LOG2E_F   (1.4426950408889634f)

typedef unsigned int uint;
typedef short  bf16x8 __attribute__((ext_vector_type(8)));
typedef float  f32x4  __attribute__((ext_vector_type(4)));

__device__ inline float fast_exp2(float x) {
#if __has_builtin(__builtin_amdgcn_exp2f)
    return __builtin_amdgcn_exp2f(x);      // raw v_exp_f32
#else
    return __expf(x * 0.6931471805599453f);
#endif
}

__device__ inline uint bf16_rne(float x) {   // round-to-nearest-even bf16 bits
    uint u = __builtin_bit_cast(uint, x);
    return (u + 0x7fffu + ((u >> 16) & 1u)) >> 16;
}

// ---------------------------------------------------------------------------
// prep kernel: three independent jobs split by blockIdx range.
//  A) blocks [0,2048):    maskM[i*16+jw] = ballot bits of adj[i][jw*64+lane]
//                         (ROW-major words: byte b of row i covers j=8b..8b+7)
//  B) blocks [2048,2112): LDS-tile transpose fc1_w [8192,54] -> wt [54,8192]
//  C) blocks [2112,2240): gat1 projection: h1 = X@W1; f11/f21 logits *log2e
// ---------------------------------------------------------------------------
__global__ __launch_bounds__(512) void prep_kernel(
        const int* __restrict__ adj, unsigned long long* __restrict__ maskM,
        const float* __restrict__ fc1w, float* __restrict__ wt,
        const float* __restrict__ X, const float* __restrict__ W1,
        const float* __restrict__ a1,
        float* __restrict__ h1, float* __restrict__ f11, float* __restrict__ f21) {
    int b = blockIdx.x;
    if (b < 2048) {
        int wave = threadIdx.x >> 6, lane = threadIdx.x & 63;
        int wid = b * 8 + wave;            // 0..16383
        int jw  = wid >> 10;               // 0..15
        int i   = wid & 1023;
        int v = adj[i * N + (jw << 6) + lane];        // coalesced 256B/wave
        unsigned long long m = __ballot(v > 0);       // bit lane = adj>0
        if (lane == 0) maskM[i * 16 + jw] = m;        // row-major
    } else if (b < 2112) {
        __shared__ float tile[128 * FC1];
        const int m0 = (b - 2048) * 128;
        const float* src = fc1w + (size_t)m0 * FC1;
        for (int idx = threadIdx.x; idx < 128 * FC1; idx += 512)
            tile[idx] = src[idx];                     // consecutive
        __syncthreads();
        for (int idx = threadIdx.x; idx < 128 * FC1; idx += 512) {
            int c = idx >> 7, mm = idx & 127;
            wt[(size_t)c * (N * DOUT) + m0 + mm] = tile[mm * FC1 + c];
        }
    } else {
        int idx = (b - 2112) * 512 + threadIdx.x;     // < 65536 : k*N+n
        const float4* x4 = (const float4*)(X + (size_t)idx * DIN);
        float h[H1] = {0.f, 0.f, 0.f, 0.f};
        #pragma unroll
        for (int q = 0; q < 4; q++) {
            float4 xv = x4[q];
            #pragma unroll
            for (int f = 0; f < H1; f++) {
                h[f] += xv.x * W1[(q * 4 + 0) * H1 + f] + xv.y * W1[(q * 4 + 1) * H1 + f]
                      + xv.z * W1[(q * 4 + 2) * H1 + f] + xv.w * W1[(q * 4 + 3) * H1 + f];
            }
        }
        float s1 = 0.f, s2 = 0.f;
        #pragma unroll
        for (int f = 0; f < H1; f++) { s1 += h[f] * a1[f]; s2 += h[f] * a1[H1 + f]; }
        *(float4*)(h1 + (size_t)idx * H1) = make_float4(h[0], h[1], h[2], h[3]);
        f11[idx] = s1 * LOG2E_F;           // pre-scaled for exp2
        f21[idx] = s2 * LOG2E_F;
    }
}

// ---------------------------------------------------------------------------
// MFMA attention: per wave, one 16-row i-tile; K-loop over 32 chunks of 32 j.
// P[16x32] built per chunk directly in A-fragment layout (lane: m=lane&15,
// k=quad*8+jj); H[k] staged once per block in LDS in B-fragment layout as
// bf16 with an appended ones column (n=F) -> one MFMA chain yields both
// sum(p*h) (cols 0..F-1) and the softmax denominator sum(p) (col F).
// Mask: row-major words; dword c of row i = the 4 quad-bytes of chunk c.
// Softmax without max-subtract (logits pre-scaled by log2e -> raw exp2;
// mask zeroes p before pack -> exact).  Block 512 thr = 8 waves = 8 i-tiles;
// grid K*8 -> 2 blocks/CU (LDS 39 KB), 4 waves/SIMD.
// FUSE (layer 1): layer-2 projection via wave-local LDS transpose epilogue.
// ---------------------------------------------------------------------------
template <int F, bool FUSE>
__global__ __launch_bounds__(512, 4) void gat_attn_mfma(
        const unsigned long long* __restrict__ maskM,  // [N][16] row-major
        const float* __restrict__ h,    // [K,N,F]
        const float* __restrict__ f1,   // [K,N]  (x log2e)
        const float* __restrict__ f2,   // [K,N]  (x log2e)
        const float* __restrict__ W2,   // [4,8]  (FUSE only)
        const float* __restrict__ a2,   // [16]   (FUSE only)
        float* __restrict__ o_x,        // FUSE: h2 [K,N,8]; else out [K,N,F]
        float* __restrict__ o_f1,       // FUSE: f12 (x log2e)
        float* __restrict__ o_f2) {     // FUSE: f22 (x log2e)
    __shared__ uint4 HB[2048];          // B-frags: [chunk][lane] 8 bf16 (32 KB)
    __shared__ float F2s[1024];         // f2[k] (4 KB)
    __shared__ float XP[8][16][5];      // FUSE transpose scratch (2.5 KB)

    const int tid  = threadIdx.x;
    const int lane = tid & 63;
    const int wv   = tid >> 6;
    const int quad = lane >> 4;
    const int n16  = lane & 15;
    const int k    = blockIdx.x >> 3;

    // ---- stage H (B-fragment layout, bf16, + ones column) and f2 ----
    {
        const float* hk = h + (size_t)k * N * F;
        #pragma unroll
        for (int e = tid; e < 2048; e += 512) {
            int c = e >> 6, l = e & 63, q = l >> 4, n = l & 15;
            uint4 dw;
            if (n < F) {
                const float* hp = hk + (size_t)(c * 32 + q * 8) * F + n;
                dw.x = bf16_rne(hp[0])     | (bf16_rne(hp[F])     << 16);
                dw.y = bf16_rne(hp[2 * F]) | (bf16_rne(hp[3 * F]) << 16);
                dw.z = bf16_rne(hp[4 * F]) | (bf16_rne(hp[5 * F]) << 16);
                dw.w = bf16_rne(hp[6 * F]) | (bf16_rne(hp[7 * F]) << 16);
            } else if (n == F) {
                dw = make_uint4(0x3f803f80u, 0x3f803f80u, 0x3f803f80u, 0x3f803f80u);
            } else {
                dw = make_uint4(0u, 0u, 0u, 0u);
            }
            HB[e] = dw;
        }
        if (tid < 256)
            ((float4*)F2s)[tid] = ((const float4*)(f2 + k * N))[tid];
    }
    __syncthreads();

    const int itile = (blockIdx.x & 7) * 8 + wv;     // 0..63
    const int ibase = itile * 16;
    const int irow  = ibase + n16;                   // this lane's P row
    const float f1v = f1[k * N + irow];

    // mask row: 32 dwords; dword c = quad-bytes of chunk c
    uint4 M[8];
    {
        const uint4* mrow = (const uint4*)((const char*)maskM + (size_t)irow * 128);
        #pragma unroll
        for (int g = 0; g < 8; g++) M[g] = mrow[g];
    }

    f32x4 acc = {0.f, 0.f, 0.f, 0.f};
    union { bf16x8 v; uint u[4]; } af;
    union { bf16x8 v; uint4 q; }  bfrag;

    #pragma unroll
    for (int c = 0; c < 32; c++) {
        uint4 Mg = M[c >> 2];
        uint mdw = ((c & 3) == 0) ? Mg.x : ((c & 3) == 1) ? Mg.y
                 : ((c & 3) == 2) ? Mg.z : Mg.w;
        uint mb  = (mdw >> (quad * 8)) & 0xffu;      // 8 mask bits for this lane
        float4 fa = *(const float4*)(F2s + c * 32 + quad * 8);
        float4 fb = *(const float4*)(F2s + c * 32 + quad * 8 + 4);
        float f2e[8] = {fa.x, fa.y, fa.z, fa.w, fb.x, fb.y, fb.z, fb.w};
        float pv[8];
        #pragma unroll
        for (int jj = 0; jj < 8; jj++) {
            float x = f1v + f2e[jj];
            float e = fmaxf(x, ALPHA_F * x);         // leaky (log2-scaled)
            float p = fast_exp2(e);
            pv[jj] = (mb & (1u << jj)) ? p : 0.f;    // mask -> exact 0
        }
        #pragma unroll
        for (int pr = 0; pr < 4; pr++)
            af.u[pr] = bf16_rne(pv[2 * pr]) | (bf16_rne(pv[2 * pr + 1]) << 16);
        bfrag.q = HB[c * 64 + lane];
        acc = __builtin_amdgcn_mfma_f32_16x16x32_bf16(af.v, bfrag.v, acc, 0, 0, 0);
    }

    // ---- epilogue: C[m][n]: n=lane&15, m=quad*4+reg; denom in col n==F ----
    #pragma unroll
    for (int r = 0; r < 4; r++) {
        float den = __shfl(acc[r], (lane & 48) + F);
        float inv = (den > 0.f) ? 1.f / den : 0.f;
        float xo  = fmaxf(acc[r] * inv, 0.f);        // relu
        int m = quad * 4 + r;
        if constexpr (FUSE) {
            if (n16 < F) XP[wv][m][n16] = xo;
        } else {
            if (n16 < F) o_x[((size_t)k * N + ibase + m) * F + n16] = xo;
        }
    }

    if constexpr (FUSE) {
        __syncthreads();
        if (lane < 16) {
            int m = lane;
            float x0 = XP[wv][m][0], x1 = XP[wv][m][1];
            float x2v = XP[wv][m][2], x3 = XP[wv][m][3];
            float hv[DOUT];
            #pragma unroll
            for (int f = 0; f < DOUT; f++) {
                hv[f] = x0 * W2[f]      + x1 * W2[8 + f]
                      + x2v * W2[16 + f] + x3 * W2[24 + f];
            }
            float t1 = 0.f, t2 = 0.f;
            #pragma unroll
            for (int f = 0; f < DOUT; f++) { t1 += hv[f] * a2[f]; t2 += hv[f] * a2[DOUT + f]; }
            const int row = k * N + ibase + m;
            float* op = o_x + (size_t)row * DOUT;
            *(float4*)op       = make_float4(hv[0], hv[1], hv[2], hv[3]);
            *(float4*)(op + 4) = make_float4(hv[4], hv[5], hv[6], hv[7]);
            o_f1[row] = t1 * LOG2E_F;
            o_f2[row] = t2 * LOG2E_F;
        }
    }
}

// ---------------------------------------------------------------------------
// FC1: y[k,c] = relu( x2[k,:] . wt[c,:] + b[c] ).  (R8 structure)
// ---------------------------------------------------------------------------
__global__ __launch_bounds__(256) void fc1_kernel(
        const float* __restrict__ x2, const float* __restrict__ wt,
        const float* __restrict__ b, float* __restrict__ y) {
    const int bid  = blockIdx.x;            // k*54 + c
    const int k    = bid / FC1;
    const int c    = bid - k * FC1;
    const int wave = threadIdx.x >> 6;
    const int lane = threadIdx.x & 63;
    const float4* x4 = (const float4*)(x2 + (size_t)k * N * DOUT) + wave * 512 + lane;
    const float4* w4 = (const float4*)(wt + (size_t)c * N * DOUT) + wave * 512 + lane;
    float s0 = 0.f, s1 = 0.f;
    #pragma unroll
    for (int q = 0; q < 8; q += 2) {
        float4 a0 = x4[q * 64],      w0 = w4[q * 64];
        float4 a1 = x4[q * 64 + 64], w1 = w4[q * 64 + 64];
        s0 += a0.x * w0.x + a0.y * w0.y + a0.z * w0.z + a0.w * w0.w;
        s1 += a1.x * w1.x + a1.y * w1.y + a1.z * w1.z + a1.w * w1.w;
    }
    float s = s0 + s1;
    #pragma unroll
    for (int off = 32; off > 0; off >>= 1) s += __shfl_xor(s, off);
    __shared__ float red[4];
    if (lane == 0) red[wave] = s;
    __syncthreads();
    if (threadIdx.x == 0)
        y[bid] = fmaxf(red[0] + red[1] + red[2] + red[3] + b[c], 0.f);
}

// ---------------------------------------------------------------------------
// Final: out[k,n] = y[k,:] . out_w[:,n] + out_b[n].  One thread per (k,n).
// ---------------------------------------------------------------------------
__global__ void fc2_kernel(const float* __restrict__ y,
                           const float* __restrict__ out_w,
                           const float* __restrict__ out_b,
                           float* __restrict__ out) {
    int n = blockIdx.x * blockDim.x + threadIdx.x;   // 0..1023
    int k = blockIdx.y;
    const float* yk = y + (size_t)k * FC1;
    float s = out_b[n];
    #pragma unroll 6
    for (int c = 0; c < FC1; c++) s += yk[c] * out_w[(size_t)c * N + n];
    out[(size_t)k * N + n] = s;
}

// ---------------------------------------------------------------------------
extern "C" void kernel_launch(void* const* d_in, const int* in_sizes, int n_in,
                              void* d_out, int out_size, void* d_ws, size_t ws_size,
                              hipStream_t stream) {
    const float* X     = (const float*)d_in[0];
    const int*   adj   = (const int*)  d_in[1];
    const float* W1    = (const float*)d_in[2];
    const float* a1    = (const float*)d_in[3];
    const float* W2    = (const float*)d_in[4];
    const float* a2    = (const float*)d_in[5];
    const float* fc1w  = (const float*)d_in[6];
    const float* fc1b  = (const float*)d_in[7];
    const float* outw  = (const float*)d_in[8];
    const float* outb  = (const float*)d_in[9];
    float* out = (float*)d_out;

    // Workspace layout (floats); ~8 MB total
    float* ws  = (float*)d_ws;
    float* h1  = ws;                       // 262144
    float* f11 = h1  + 262144;             // 65536
    float* f21 = f11 + 65536;              // 65536
    float* h2  = f21 + 65536;              // 524288
    float* f12 = h2  + 524288;             // 65536
    float* f22 = f12 + 65536;              // 65536
    float* x2  = f22 + 65536;              // 524288
    float* y   = x2  + 524288;             // 4096 (3456 used)
    float* wt  = y   + 4096;               // 442368
    unsigned long long* mM = (unsigned long long*)(wt + 442368);  // 16384 u64

    // 1) fused prep: row-major mask pack + fc1_w transpose + gat1 proj
    prep_kernel<<<dim3(2240), dim3(512), 0, stream>>>(
        adj, mM, fc1w, wt, X, W1, a1, h1, f11, f21);

    // 2) layer-1 attention (MFMA aggregation), fused layer-2 projection
    gat_attn_mfma<4, true><<<dim3(K * 8), dim3(512), 0, stream>>>(
        mM, h1, f11, f21, W2, a2, h2, f12, f22);

    // 3) layer-2 attention (MFMA aggregation)
    gat_attn_mfma<8, false><<<dim3(K * 8), dim3(512), 0, stream>>>(
        mM, h2, f12, f22, nullptr, nullptr, x2, nullptr, nullptr);

    // 4) FC head (R8 structure)
    fc1_kernel<<<dim3(K * FC1), dim3(256), 0, stream>>>(x2, wt, fc1b, y);
    fc2_kernel<<<dim3(N / 256, K), dim3(256), 0, stream>>>(y, outw, outb, out);
}

// Round 11
// 139.346 us; speedup vs baseline: 1.3187x; 1.0482x over previous
//
#include <hip/hip_runtime.h>
#include <hip/hip_bf16.h>

// Problem constants (from reference setup_inputs)
constexpr int K    = 64;
constexpr int N    = 1024;
constexpr int DIN  = 16;
constexpr int H1   = 4;
constexpr int DOUT = 8;
constexpr int FC1  = 54;

#define ALPHA_F   (0.01f)
#define LOG2E_F   (1.4426950408889634f)

typedef unsigned int uint;
typedef short  bf16x8 __attribute__((ext_vector_type(8)));
typedef float  f32x4  __attribute__((ext_vector_type(4)));

__device__ inline float fast_exp2(float x) {
#if __has_builtin(__builtin_amdgcn_exp2f)
    return __builtin_amdgcn_exp2f(x);      // raw v_exp_f32
#else
    return __expf(x * 0.6931471805599453f);
#endif
}

// packed bf16 pair (RNE) -> uint (lo = a, hi = b); v_cvt_pk_bf16_f32 on gfx950
__device__ inline uint pk_bf16(float a, float b) {
    union { __hip_bfloat162 h; uint u; } v;
    v.h = __float22bfloat162_rn(make_float2(a, b));
    return v.u;
}

// ---------------------------------------------------------------------------
// prep kernel: three independent jobs split by blockIdx range.
//  A) blocks [0,2048):    maskM[i*16+jw] = ballot bits of adj[i][jw*64+lane]
//                         (ROW-major words: byte b of row i covers j=8b..8b+7)
//  B) blocks [2048,2112): LDS-tile transpose fc1_w [8192,54] -> wt [54,8192]
//  C) blocks [2112,2240): gat1 projection: h1 = X@W1; f11/f21 logits *log2e
// ---------------------------------------------------------------------------
__global__ __launch_bounds__(512) void prep_kernel(
        const int* __restrict__ adj, unsigned long long* __restrict__ maskM,
        const float* __restrict__ fc1w, float* __restrict__ wt,
        const float* __restrict__ X, const float* __restrict__ W1,
        const float* __restrict__ a1,
        float* __restrict__ h1, float* __restrict__ f11, float* __restrict__ f21) {
    int b = blockIdx.x;
    if (b < 2048) {
        int wave = threadIdx.x >> 6, lane = threadIdx.x & 63;
        int wid = b * 8 + wave;            // 0..16383
        int jw  = wid >> 10;               // 0..15
        int i   = wid & 1023;
        int v = adj[i * N + (jw << 6) + lane];        // coalesced 256B/wave
        unsigned long long m = __ballot(v > 0);       // bit lane = adj>0
        if (lane == 0) maskM[i * 16 + jw] = m;        // row-major
    } else if (b < 2112) {
        __shared__ float tile[128 * FC1];
        const int m0 = (b - 2048) * 128;
        const float* src = fc1w + (size_t)m0 * FC1;
        for (int idx = threadIdx.x; idx < 128 * FC1; idx += 512)
            tile[idx] = src[idx];                     // consecutive
        __syncthreads();
        for (int idx = threadIdx.x; idx < 128 * FC1; idx += 512) {
            int c = idx >> 7, mm = idx & 127;
            wt[(size_t)c * (N * DOUT) + m0 + mm] = tile[mm * FC1 + c];
        }
    } else {
        int idx = (b - 2112) * 512 + threadIdx.x;     // < 65536 : k*N+n
        const float4* x4 = (const float4*)(X + (size_t)idx * DIN);
        float h[H1] = {0.f, 0.f, 0.f, 0.f};
        #pragma unroll
        for (int q = 0; q < 4; q++) {
            float4 xv = x4[q];
            #pragma unroll
            for (int f = 0; f < H1; f++) {
                h[f] += xv.x * W1[(q * 4 + 0) * H1 + f] + xv.y * W1[(q * 4 + 1) * H1 + f]
                      + xv.z * W1[(q * 4 + 2) * H1 + f] + xv.w * W1[(q * 4 + 3) * H1 + f];
            }
        }
        float s1 = 0.f, s2 = 0.f;
        #pragma unroll
        for (int f = 0; f < H1; f++) { s1 += h[f] * a1[f]; s2 += h[f] * a1[H1 + f]; }
        *(float4*)(h1 + (size_t)idx * H1) = make_float4(h[0], h[1], h[2], h[3]);
        f11[idx] = s1 * LOG2E_F;           // pre-scaled for exp2
        f21[idx] = s2 * LOG2E_F;
    }
}

// ---------------------------------------------------------------------------
// MFMA attention v2: per wave, one 16-row i-tile; K-loop = 8 groups x 4
// chunks of 32 j.  P[16x32] built per chunk in A-fragment layout (m=lane&15,
// k=quad*8+jj); H[k] staged once per block in LDS in B-fragment layout as
// bf16 with an appended ones column (n=F) -> the MFMA chain yields both
// sum(p*h) (cols 0..F-1) and the denominator sum(p) (col F).
// vs v1: HW packed bf16 cvt (v_cvt_pk_bf16_f32) instead of manual RNE
// (~28 -> 4 ops/chunk), mask uint4 loaded per group (frees ~28 VGPRs for
// ds_read hoisting).  Softmax without max-subtract (logits pre-scaled by
// log2e -> raw exp2; mask zeroes p before pack -> exact).
// Block 512 thr = 8 waves = 8 i-tiles; grid K*8.
// FUSE (layer 1): layer-2 projection via wave-local LDS transpose epilogue.
// ---------------------------------------------------------------------------
template <int F, bool FUSE>
__global__ __launch_bounds__(512, 4) void gat_attn_mfma(
        const unsigned long long* __restrict__ maskM,  // [N][16] row-major
        const float* __restrict__ h,    // [K,N,F]
        const float* __restrict__ f1,   // [K,N]  (x log2e)
        const float* __restrict__ f2,   // [K,N]  (x log2e)
        const float* __restrict__ W2,   // [4,8]  (FUSE only)
        const float* __restrict__ a2,   // [16]   (FUSE only)
        float* __restrict__ o_x,        // FUSE: h2 [K,N,8]; else out [K,N,F]
        float* __restrict__ o_f1,       // FUSE: f12 (x log2e)
        float* __restrict__ o_f2) {     // FUSE: f22 (x log2e)
    __shared__ uint4 HB[2048];          // B-frags: [chunk][lane] 8 bf16 (32 KB)
    __shared__ float F2s[1024];         // f2[k] (4 KB)
    __shared__ float XP[8][16][5];      // FUSE transpose scratch (2.5 KB)

    const int tid  = threadIdx.x;
    const int lane = tid & 63;
    const int wv   = tid >> 6;
    const int quad = lane >> 4;
    const int n16  = lane & 15;
    const int k    = blockIdx.x >> 3;

    // ---- stage H (B-fragment layout, bf16, + ones column) and f2 ----
    {
        const float* hk = h + (size_t)k * N * F;
        #pragma unroll
        for (int e = tid; e < 2048; e += 512) {
            int c = e >> 6, l = e & 63, q = l >> 4, n = l & 15;
            uint4 dw;
            if (n < F) {
                const float* hp = hk + (size_t)(c * 32 + q * 8) * F + n;
                dw.x = pk_bf16(hp[0],     hp[F]);
                dw.y = pk_bf16(hp[2 * F], hp[3 * F]);
                dw.z = pk_bf16(hp[4 * F], hp[5 * F]);
                dw.w = pk_bf16(hp[6 * F], hp[7 * F]);
            } else if (n == F) {
                dw = make_uint4(0x3f803f80u, 0x3f803f80u, 0x3f803f80u, 0x3f803f80u);
            } else {
                dw = make_uint4(0u, 0u, 0u, 0u);
            }
            HB[e] = dw;
        }
        if (tid < 256)
            ((float4*)F2s)[tid] = ((const float4*)(f2 + k * N))[tid];
    }
    __syncthreads();

    const int itile = (blockIdx.x & 7) * 8 + wv;     // 0..63
    const int ibase = itile * 16;
    const int irow  = ibase + n16;                   // this lane's P row
    const float f1v = f1[k * N + irow];
    const uint4* mrow = (const uint4*)((const char*)maskM + (size_t)irow * 128);

    f32x4 acc = {0.f, 0.f, 0.f, 0.f};
    union { bf16x8 v; uint u[4]; } af;
    union { bf16x8 v; uint4 q; }  bfrag;

    #pragma unroll 2
    for (int g = 0; g < 8; g++) {
        const uint4 Mg = mrow[g];                    // 4 chunks of mask bits
        #pragma unroll
        for (int cc = 0; cc < 4; cc++) {
            const int c = g * 4 + cc;
            const uint mdw = (cc == 0) ? Mg.x : (cc == 1) ? Mg.y
                           : (cc == 2) ? Mg.z : Mg.w;
            const uint mb  = (mdw >> (quad * 8)) & 0xffu;  // 8 bits, this lane
            float4 fa = *(const float4*)(F2s + c * 32 + quad * 8);
            float4 fb = *(const float4*)(F2s + c * 32 + quad * 8 + 4);
            bfrag.q = HB[c * 64 + lane];
            float f2e[8] = {fa.x, fa.y, fa.z, fa.w, fb.x, fb.y, fb.z, fb.w};
            float pv[8];
            #pragma unroll
            for (int jj = 0; jj < 8; jj++) {
                float x = f1v + f2e[jj];
                float e = fmaxf(x, ALPHA_F * x);     // leaky (log2-scaled)
                float p = fast_exp2(e);
                pv[jj] = (mb & (1u << jj)) ? p : 0.f;  // mask -> exact 0
            }
            #pragma unroll
            for (int pr = 0; pr < 4; pr++)
                af.u[pr] = pk_bf16(pv[2 * pr], pv[2 * pr + 1]);
            acc = __builtin_amdgcn_mfma_f32_16x16x32_bf16(af.v, bfrag.v, acc, 0, 0, 0);
        }
    }

    // ---- epilogue: C[m][n]: n=lane&15, m=quad*4+reg; denom in col n==F ----
    #pragma unroll
    for (int r = 0; r < 4; r++) {
        float den = __shfl(acc[r], (lane & 48) + F);
        float inv = (den > 0.f) ? 1.f / den : 0.f;
        float xo  = fmaxf(acc[r] * inv, 0.f);        // relu
        int m = quad * 4 + r;
        if constexpr (FUSE) {
            if (n16 < F) XP[wv][m][n16] = xo;
        } else {
            if (n16 < F) o_x[((size_t)k * N + ibase + m) * F + n16] = xo;
        }
    }

    if constexpr (FUSE) {
        __syncthreads();
        if (lane < 16) {
            int m = lane;
            float x0 = XP[wv][m][0], x1 = XP[wv][m][1];
            float x2v = XP[wv][m][2], x3 = XP[wv][m][3];
            float hv[DOUT];
            #pragma unroll
            for (int f = 0; f < DOUT; f++) {
                hv[f] = x0 * W2[f]      + x1 * W2[8 + f]
                      + x2v * W2[16 + f] + x3 * W2[24 + f];
            }
            float t1 = 0.f, t2 = 0.f;
            #pragma unroll
            for (int f = 0; f < DOUT; f++) { t1 += hv[f] * a2[f]; t2 += hv[f] * a2[DOUT + f]; }
            const int row = k * N + ibase + m;
            float* op = o_x + (size_t)row * DOUT;
            *(float4*)op       = make_float4(hv[0], hv[1], hv[2], hv[3]);
            *(float4*)(op + 4) = make_float4(hv[4], hv[5], hv[6], hv[7]);
            o_f1[row] = t1 * LOG2E_F;
            o_f2[row] = t2 * LOG2E_F;
        }
    }
}

// ---------------------------------------------------------------------------
// FC1: y[k,c] = relu( x2[k,:] . wt[c,:] + b[c] ).  (R8 structure)
// ---------------------------------------------------------------------------
__global__ __launch_bounds__(256) void fc1_kernel(
        const float* __restrict__ x2, const float* __restrict__ wt,
        const float* __restrict__ b, float* __restrict__ y) {
    const int bid  = blockIdx.x;            // k*54 + c
    const int k    = bid / FC1;
    const int c    = bid - k * FC1;
    const int wave = threadIdx.x >> 6;
    const int lane = threadIdx.x & 63;
    const float4* x4 = (const float4*)(x2 + (size_t)k * N * DOUT) + wave * 512 + lane;
    const float4* w4 = (const float4*)(wt + (size_t)c * N * DOUT) + wave * 512 + lane;
    float s0 = 0.f, s1 = 0.f;
    #pragma unroll
    for (int q = 0; q < 8; q += 2) {
        float4 a0 = x4[q * 64],      w0 = w4[q * 64];
        float4 a1 = x4[q * 64 + 64], w1 = w4[q * 64 + 64];
        s0 += a0.x * w0.x + a0.y * w0.y + a0.z * w0.z + a0.w * w0.w;
        s1 += a1.x * w1.x + a1.y * w1.y + a1.z * w1.z + a1.w * w1.w;
    }
    float s = s0 + s1;
    #pragma unroll
    for (int off = 32; off > 0; off >>= 1) s += __shfl_xor(s, off);
    __shared__ float red[4];
    if (lane == 0) red[wave] = s;
    __syncthreads();
    if (threadIdx.x == 0)
        y[bid] = fmaxf(red[0] + red[1] + red[2] + red[3] + b[c], 0.f);
}

// ---------------------------------------------------------------------------
// Final: out[k,n] = y[k,:] . out_w[:,n] + out_b[n].  One thread per (k,n).
// ---------------------------------------------------------------------------
__global__ void fc2_kernel(const float* __restrict__ y,
                           const float* __restrict__ out_w,
                           const float* __restrict__ out_b,
                           float* __restrict__ out) {
    int n = blockIdx.x * blockDim.x + threadIdx.x;   // 0..1023
    int k = blockIdx.y;
    const float* yk = y + (size_t)k * FC1;
    float s = out_b[n];
    #pragma unroll 6
    for (int c = 0; c < FC1; c++) s += yk[c] * out_w[(size_t)c * N + n];
    out[(size_t)k * N + n] = s;
}

// ---------------------------------------------------------------------------
extern "C" void kernel_launch(void* const* d_in, const int* in_sizes, int n_in,
                              void* d_out, int out_size, void* d_ws, size_t ws_size,
                              hipStream_t stream) {
    const float* X     = (const float*)d_in[0];
    const int*   adj   = (const int*)  d_in[1];
    const float* W1    = (const float*)d_in[2];
    const float* a1    = (const float*)d_in[3];
    const float* W2    = (const float*)d_in[4];
    const float* a2    = (const float*)d_in[5];
    const float* fc1w  = (const float*)d_in[6];
    const float* fc1b  = (const float*)d_in[7];
    const float* outw  = (const float*)d_in[8];
    const float* outb  = (const float*)d_in[9];
    float* out = (float*)d_out;

    // Workspace layout (floats); ~8 MB total
    float* ws  = (float*)d_ws;
    float* h1  = ws;                       // 262144
    float* f11 = h1  + 262144;             // 65536
    float* f21 = f11 + 65536;              // 65536
    float* h2  = f21 + 65536;              // 524288
    float* f12 = h2  + 524288;             // 65536
    float* f22 = f12 + 65536;              // 65536
    float* x2  = f22 + 65536;              // 524288
    float* y   = x2  + 524288;             // 4096 (3456 used)
    float* wt  = y   + 4096;               // 442368
    unsigned long long* mM = (unsigned long long*)(wt + 442368);  // 16384 u64

    // 1) fused prep: row-major mask pack + fc1_w transpose + gat1 proj
    prep_kernel<<<dim3(2240), dim3(512), 0, stream>>>(
        adj, mM, fc1w, wt, X, W1, a1, h1, f11, f21);

    // 2) layer-1 attention (MFMA aggregation), fused layer-2 projection
    gat_attn_mfma<4, true><<<dim3(K * 8), dim3(512), 0, stream>>>(
        mM, h1, f11, f21, W2, a2, h2, f12, f22);

    // 3) layer-2 attention (MFMA aggregation)
    gat_attn_mfma<8, false><<<dim3(K * 8), dim3(512), 0, stream>>>(
        mM, h2, f12, f22, nullptr, nullptr, x2, nullptr, nullptr);

    // 4) FC head (R8 structure)
    fc1_kernel<<<dim3(K * FC1), dim3(256), 0, stream>>>(x2, wt, fc1b, y);
    fc2_kernel<<<dim3(N / 256, K), dim3(256), 0, stream>>>(y, outw, outb, out);
}

// Round 12
// 134.747 us; speedup vs baseline: 1.3637x; 1.0341x over previous
//
#include <hip/hip_runtime.h>
#include <hip/hip_bf16.h>

// Problem constants (from reference setup_inputs)
constexpr int K    = 64;
constexpr int N    = 1024;
constexpr int DIN  = 16;
constexpr int H1   = 4;
constexpr int DOUT = 8;
constexpr int FC1  = 54;

#define ALPHA_F   (0.01f)
#define LOG2E_F   (1.4426950408889634f)

typedef unsigned int uint;
typedef short  bf16x8 __attribute__((ext_vector_type(8)));
typedef float  f32x4  __attribute__((ext_vector_type(4)));

__device__ inline float fast_exp2(float x) {
#if __has_builtin(__builtin_amdgcn_exp2f)
    return __builtin_amdgcn_exp2f(x);      // raw v_exp_f32
#else
    return __expf(x * 0.6931471805599453f);
#endif
}

// packed bf16 pair (RNE) -> uint (lo=a, hi=b); v_cvt_pk_bf16_f32 on gfx950
__device__ inline uint pk_bf16(float a, float b) {
    union { __hip_bfloat162 h; uint u; } v;
    v.h = __float22bfloat162_rn(make_float2(a, b));
    return v.u;
}

// ---------------------------------------------------------------------------
// B-fragment table layout (consumed by mfma_f32_16x16x32_bf16):
//   HB[k][c][lane] : uint4;  lane=(q=lane>>4, n=lane&15)
//   dword t packs rows j=c*32+q*8+2t, +2t+1 of column n:
//   n<F -> bf16(h[j][n]); n==F -> 1.0 (denominator column); n>F -> 0.
// ---------------------------------------------------------------------------

// ---------------------------------------------------------------------------
// prep kernel: three independent jobs split by blockIdx range.
//  A) blocks [0,2048):    maskM[i*16+jw] = ballot bits of adj[i][jw*64+lane]
//                         (ROW-major words: byte b of row i covers j=8b..8b+7)
//  B) blocks [2048,2112): LDS-tile transpose fc1_w [8192,54] -> wt [54,8192]
//  C) blocks [2112,2240): gat1 proj h=X@W1 -> f11/f21 logits (*log2e) AND
//                         HB1 bf16 B-fragment table (via LDS row-stage)
// ---------------------------------------------------------------------------
__global__ __launch_bounds__(512) void prep_kernel(
        const int* __restrict__ adj, unsigned long long* __restrict__ maskM,
        const float* __restrict__ fc1w, float* __restrict__ wt,
        const float* __restrict__ X, const float* __restrict__ W1,
        const float* __restrict__ a1,
        uint4* __restrict__ HB1, float* __restrict__ f11, float* __restrict__ f21) {
    int b = blockIdx.x;
    if (b < 2048) {
        int wave = threadIdx.x >> 6, lane = threadIdx.x & 63;
        int wid = b * 8 + wave;            // 0..16383
        int jw  = wid >> 10;               // 0..15
        int i   = wid & 1023;
        int v = adj[i * N + (jw << 6) + lane];        // coalesced 256B/wave
        unsigned long long m = __ballot(v > 0);       // bit lane = adj>0
        if (lane == 0) maskM[i * 16 + jw] = m;        // row-major
    } else if (b < 2112) {
        __shared__ float tile[128 * FC1];
        const int m0 = (b - 2048) * 128;
        const float* src = fc1w + (size_t)m0 * FC1;
        for (int idx = threadIdx.x; idx < 128 * FC1; idx += 512)
            tile[idx] = src[idx];                     // consecutive
        __syncthreads();
        for (int idx = threadIdx.x; idx < 128 * FC1; idx += 512) {
            int c = idx >> 7, mm = idx & 127;
            wt[(size_t)c * (N * DOUT) + m0 + mm] = tile[mm * FC1 + c];
        }
    } else {
        __shared__ float hrow[512 * 4];               // 8 KB row-stage
        const int bb  = b - 2112;                     // 0..127
        const int k   = bb >> 1;
        const int j0  = (bb & 1) * 512;
        const int tid = threadIdx.x;
        const int idx = k * N + j0 + tid;             // this thread's (k,j)
        const float4* x4 = (const float4*)(X + (size_t)idx * DIN);
        float hv_[H1] = {0.f, 0.f, 0.f, 0.f};
        #pragma unroll
        for (int q = 0; q < 4; q++) {
            float4 xv = x4[q];
            #pragma unroll
            for (int f = 0; f < H1; f++) {
                hv_[f] += xv.x * W1[(q * 4 + 0) * H1 + f] + xv.y * W1[(q * 4 + 1) * H1 + f]
                        + xv.z * W1[(q * 4 + 2) * H1 + f] + xv.w * W1[(q * 4 + 3) * H1 + f];
            }
        }
        float s1 = 0.f, s2 = 0.f;
        #pragma unroll
        for (int f = 0; f < H1; f++) { s1 += hv_[f] * a1[f]; s2 += hv_[f] * a1[H1 + f]; }
        f11[idx] = s1 * LOG2E_F;
        f21[idx] = s2 * LOG2E_F;
        #pragma unroll
        for (int f = 0; f < H1; f++) hrow[tid * 4 + f] = hv_[f];
        __syncthreads();
        // frag writes: local chunks cl=0..15 -> global chunks j0/32+cl
        uint4* HBk = HB1 + (size_t)k * 2048 + (j0 >> 5) * 64;
        #pragma unroll
        for (int e = tid; e < 1024; e += 512) {
            int cl = e >> 6, l = e & 63, q = (l >> 4), n = l & 15;
            uint4 dw;
            if (n < H1) {
                const float* hp = hrow + (cl * 32 + q * 8) * 4 + n;
                dw.x = pk_bf16(hp[0],  hp[4]);
                dw.y = pk_bf16(hp[8],  hp[12]);
                dw.z = pk_bf16(hp[16], hp[20]);
                dw.w = pk_bf16(hp[24], hp[28]);
            } else if (n == H1) {
                dw = make_uint4(0x3f803f80u, 0x3f803f80u, 0x3f803f80u, 0x3f803f80u);
            } else {
                dw = make_uint4(0u, 0u, 0u, 0u);
            }
            HBk[cl * 64 + l] = dw;
        }
    }
}

// ---------------------------------------------------------------------------
// MFMA attention v3: B-fragments from GLOBAL (coalesced VMEM, L2-resident
// 2 MB table) — no per-block H staging, no staging barrier; LDS carries only
// f2 (4 KB, quad-broadcast reads).  P[16x32] built per chunk in A-fragment
// layout; ones-column in HB gives the denominator in acc col F.
// Block 512 thr = 8 waves = 8 i-tiles; grid K*8.
// FUSE (layer 1): epilogue computes layer-2 projection AND writes the HB2
// fragment table directly (wave-local LDS transpose), plus f12/f22.
// ---------------------------------------------------------------------------
template <int F, bool FUSE>
__global__ __launch_bounds__(512, 4) void gat_attn_mfma(
        const unsigned long long* __restrict__ maskM,  // [N][16] row-major
        const uint4* __restrict__ HBin,  // [K][32][64] B-frags
        const float* __restrict__ f1,    // [K,N]  (x log2e)
        const float* __restrict__ f2,    // [K,N]  (x log2e)
        const float* __restrict__ W2,    // [4,8]  (FUSE only)
        const float* __restrict__ a2,    // [16]   (FUSE only)
        uint4* __restrict__ HBout,       // FUSE: HB2 table
        float* __restrict__ o_x,         // !FUSE: out rows [K,N,F]
        float* __restrict__ o_f1,        // FUSE: f12 (x log2e)
        float* __restrict__ o_f2) {      // FUSE: f22 (x log2e)
    __shared__ float F2s[1024];          // f2[k] (4 KB)
    __shared__ float XPa[8][16][5];      // FUSE: attn output xo
    __shared__ float XPb[8][16][9];      // FUSE: projected hv

    const int tid  = threadIdx.x;
    const int lane = tid & 63;
    const int wv   = tid >> 6;
    const int quad = lane >> 4;
    const int n16  = lane & 15;
    const int k    = blockIdx.x >> 3;

    if (tid < 256)
        ((float4*)F2s)[tid] = ((const float4*)(f2 + k * N))[tid];
    __syncthreads();

    const int itile = (blockIdx.x & 7) * 8 + wv;     // 0..63
    const int ibase = itile * 16;
    const int irow  = ibase + n16;                   // this lane's P row
    const float f1v = f1[k * N + irow];
    const uint4* mrow = (const uint4*)((const char*)maskM + (size_t)irow * 128);
    const uint4* HBk  = HBin + (size_t)k * 2048;

    f32x4 acc = {0.f, 0.f, 0.f, 0.f};
    union { bf16x8 v; uint u[4]; } af;
    union { bf16x8 v; uint4 q; }  bfrag;

    #pragma unroll 2
    for (int g = 0; g < 8; g++) {
        const uint4 Mg = mrow[g];                    // 4 chunks of mask bits
        #pragma unroll
        for (int cc = 0; cc < 4; cc++) {
            const int c = g * 4 + cc;
            const uint mdw = (cc == 0) ? Mg.x : (cc == 1) ? Mg.y
                           : (cc == 2) ? Mg.z : Mg.w;
            const uint mb  = (mdw >> (quad * 8)) & 0xffu;  // 8 bits, this lane
            float4 fa = *(const float4*)(F2s + c * 32 + quad * 8);
            float4 fb = *(const float4*)(F2s + c * 32 + quad * 8 + 4);
            bfrag.q = HBk[c * 64 + lane];            // coalesced VMEM (L2)
            float f2e[8] = {fa.x, fa.y, fa.z, fa.w, fb.x, fb.y, fb.z, fb.w};
            float pv[8];
            #pragma unroll
            for (int jj = 0; jj < 8; jj++) {
                float x = f1v + f2e[jj];
                float e = fmaxf(x, ALPHA_F * x);     // leaky (log2-scaled)
                float p = fast_exp2(e);
                pv[jj] = (mb & (1u << jj)) ? p : 0.f;  // mask -> exact 0
            }
            #pragma unroll
            for (int pr = 0; pr < 4; pr++)
                af.u[pr] = pk_bf16(pv[2 * pr], pv[2 * pr + 1]);
            acc = __builtin_amdgcn_mfma_f32_16x16x32_bf16(af.v, bfrag.v, acc, 0, 0, 0);
        }
    }

    // ---- epilogue: C[m][n]: n=lane&15, m=quad*4+reg; denom in col n==F ----
    #pragma unroll
    for (int r = 0; r < 4; r++) {
        float den = __shfl(acc[r], (lane & 48) + F);
        float inv = (den > 0.f) ? 1.f / den : 0.f;
        float xo  = fmaxf(acc[r] * inv, 0.f);        // relu
        int m = quad * 4 + r;
        if constexpr (FUSE) {
            if (n16 < F) XPa[wv][m][n16] = xo;
        } else {
            if (n16 < F) o_x[((size_t)k * N + ibase + m) * F + n16] = xo;
        }
    }

    if constexpr (FUSE) {
        __syncthreads();
        if (lane < 16) {
            const int m = lane;
            float x0 = XPa[wv][m][0], x1 = XPa[wv][m][1];
            float x2v = XPa[wv][m][2], x3 = XPa[wv][m][3];
            float hv[DOUT];
            #pragma unroll
            for (int f = 0; f < DOUT; f++) {
                hv[f] = x0 * W2[f]      + x1 * W2[8 + f]
                      + x2v * W2[16 + f] + x3 * W2[24 + f];
            }
            float t1 = 0.f, t2 = 0.f;
            #pragma unroll
            for (int f = 0; f < DOUT; f++) { t1 += hv[f] * a2[f]; t2 += hv[f] * a2[DOUT + f]; }
            const int row = k * N + ibase + m;
            o_f1[row] = t1 * LOG2E_F;
            o_f2[row] = t2 * LOG2E_F;
            #pragma unroll
            for (int f = 0; f < DOUT; f++) XPb[wv][m][f] = hv[f];
        }
        __syncthreads();
        if (lane < 32) {
            const int c2    = ibase >> 5;
            const int qhalf = (ibase >> 4) & 1;
            const int ql    = lane >> 4;
            const int n     = lane & 15;
            const int q     = qhalf * 2 + ql;
            uint4 dw;
            if (n < DOUT) {
                dw.x = pk_bf16(XPb[wv][ql * 8 + 0][n], XPb[wv][ql * 8 + 1][n]);
                dw.y = pk_bf16(XPb[wv][ql * 8 + 2][n], XPb[wv][ql * 8 + 3][n]);
                dw.z = pk_bf16(XPb[wv][ql * 8 + 4][n], XPb[wv][ql * 8 + 5][n]);
                dw.w = pk_bf16(XPb[wv][ql * 8 + 6][n], XPb[wv][ql * 8 + 7][n]);
            } else if (n == DOUT) {
                dw = make_uint4(0x3f803f80u, 0x3f803f80u, 0x3f803f80u, 0x3f803f80u);
            } else {
                dw = make_uint4(0u, 0u, 0u, 0u);
            }
            HBout[(size_t)k * 2048 + c2 * 64 + q * 16 + n] = dw;
        }
    }
}

// ---------------------------------------------------------------------------
// FC1: y[k,c] = relu( x2[k,:] . wt[c,:] + b[c] ).  (R8 structure)
// ---------------------------------------------------------------------------
__global__ __launch_bounds__(256) void fc1_kernel(
        const float* __restrict__ x2, const float* __restrict__ wt,
        const float* __restrict__ b, float* __restrict__ y) {
    const int bid  = blockIdx.x;            // k*54 + c
    const int k    = bid / FC1;
    const int c    = bid - k * FC1;
    const int wave = threadIdx.x >> 6;
    const int lane = threadIdx.x & 63;
    const float4* x4 = (const float4*)(x2 + (size_t)k * N * DOUT) + wave * 512 + lane;
    const float4* w4 = (const float4*)(wt + (size_t)c * N * DOUT) + wave * 512 + lane;
    float s0 = 0.f, s1 = 0.f;
    #pragma unroll
    for (int q = 0; q < 8; q += 2) {
        float4 a0 = x4[q * 64],      w0 = w4[q * 64];
        float4 a1 = x4[q * 64 + 64], w1 = w4[q * 64 + 64];
        s0 += a0.x * w0.x + a0.y * w0.y + a0.z * w0.z + a0.w * w0.w;
        s1 += a1.x * w1.x + a1.y * w1.y + a1.z * w1.z + a1.w * w1.w;
    }
    float s = s0 + s1;
    #pragma unroll
    for (int off = 32; off > 0; off >>= 1) s += __shfl_xor(s, off);
    __shared__ float red[4];
    if (lane == 0) red[wave] = s;
    __syncthreads();
    if (threadIdx.x == 0)
        y[bid] = fmaxf(red[0] + red[1] + red[2] + red[3] + b[c], 0.f);
}

// ---------------------------------------------------------------------------
// Final: out[k,n] = y[k,:] . out_w[:,n] + out_b[n].  One thread per (k,n).
// ---------------------------------------------------------------------------
__global__ void fc2_kernel(const float* __restrict__ y,
                           const float* __restrict__ out_w,
                           const float* __restrict__ out_b,
                           float* __restrict__ out) {
    int n = blockIdx.x * blockDim.x + threadIdx.x;   // 0..1023
    int k = blockIdx.y;
    const float* yk = y + (size_t)k * FC1;
    float s = out_b[n];
    #pragma unroll 6
    for (int c = 0; c < FC1; c++) s += yk[c] * out_w[(size_t)c * N + n];
    out[(size_t)k * N + n] = s;
}

// ---------------------------------------------------------------------------
extern "C" void kernel_launch(void* const* d_in, const int* in_sizes, int n_in,
                              void* d_out, int out_size, void* d_ws, size_t ws_size,
                              hipStream_t stream) {
    const float* X     = (const float*)d_in[0];
    const int*   adj   = (const int*)  d_in[1];
    const float* W1    = (const float*)d_in[2];
    const float* a1    = (const float*)d_in[3];
    const float* W2    = (const float*)d_in[4];
    const float* a2    = (const float*)d_in[5];
    const float* fc1w  = (const float*)d_in[6];
    const float* fc1b  = (const float*)d_in[7];
    const float* outw  = (const float*)d_in[8];
    const float* outb  = (const float*)d_in[9];
    float* out = (float*)d_out;

    // Workspace layout (floats); ~9.3 MB total
    float* ws  = (float*)d_ws;
    float* f11 = ws;                       // 65536
    float* f21 = f11 + 65536;              // 65536
    float* f12 = f21 + 65536;              // 65536
    float* f22 = f12 + 65536;              // 65536
    float* x2  = f22 + 65536;              // 524288
    float* y   = x2  + 524288;             // 4096 (3456 used)
    float* wt  = y   + 4096;               // 442368
    unsigned long long* mM = (unsigned long long*)(wt + 442368);   // 16384 u64
    uint4* HB1 = (uint4*)(wt + 442368 + 32768);                    // 131072 u4
    uint4* HB2 = HB1 + 131072;                                     // 131072 u4

    // 1) fused prep: mask pack + fc1_w transpose + gat1 proj -> HB1 frags
    prep_kernel<<<dim3(2240), dim3(512), 0, stream>>>(
        adj, mM, fc1w, wt, X, W1, a1, HB1, f11, f21);

    // 2) layer-1 attention (MFMA, global frags) -> HB2 frags + f12/f22
    gat_attn_mfma<4, true><<<dim3(K * 8), dim3(512), 0, stream>>>(
        mM, HB1, f11, f21, W2, a2, HB2, nullptr, f12, f22);

    // 3) layer-2 attention (MFMA, global frags) -> x2 rows
    gat_attn_mfma<8, false><<<dim3(K * 8), dim3(512), 0, stream>>>(
        mM, HB2, f12, f22, nullptr, nullptr, nullptr, x2, nullptr, nullptr);

    // 4) FC head (R8 structure)
    fc1_kernel<<<dim3(K * FC1), dim3(256), 0, stream>>>(x2, wt, fc1b, y);
    fc2_kernel<<<dim3(N / 256, K), dim3(256), 0, stream>>>(y, outw, outb, out);
}